// Round 1
// baseline (997.673 us; speedup 1.0000x reference)
//
#include <hip/hip_runtime.h>
#include <hip/hip_bf16.h>

#define NN 50000
#define NE 800000
#define HD 64
#define OD 16

typedef __hip_bfloat16 bf16;

// ---- dtype-robust load: flags[1]>1000 => float tensors are f32, else bf16 ----
__device__ __forceinline__ float ldf(const void* p, long i, bool f32m) {
  return f32m ? ((const float*)p)[i] : __bfloat162float(((const bf16*)p)[i]);
}

// ---- probe: decide int64-vs-int32 edges (flags[0]) and f32-vs-bf16 floats (flags[1]) ----
// int64 edge data: values < 50000 -> every odd u32 word is 0. int32 data: odd words are
// real indices, virtually never all zero.
// f32 x data: the LOW u16 of each f32 is random mantissa bits -> exponent field (bits 14:7)
// is uniform over [0,255]. bf16 N(0,1) data: exponent field stays in ~[118,129].
__global__ void k_detect(const unsigned int* __restrict__ e32,
                         const unsigned short* __restrict__ xu,
                         int* flags) {
  int i = blockIdx.x * blockDim.x + threadIdx.x;
  if (i < 4096) {
    if (e32[2 * i + 1] != 0u) atomicOr(&flags[0], 1);   // nonzero odd word => int32
  }
  if (i < 65536) {
    unsigned short v = xu[i];
    int e = (v >> 7) & 0xFF;
    if (v != 0 && (e < 100 || e > 140)) atomicAdd(&flags[1], 1);  // wild exponent => f32
  }
}

__global__ void k_cvt_x(const void* __restrict__ x, float* __restrict__ xf,
                        const int* __restrict__ flags) {
  bool f32m = flags[1] > 1000;
  int i = blockIdx.x * blockDim.x + threadIdx.x;
  if (i < NN * HD) xf[i] = ldf(x, i, f32m);
}

__global__ void k_cvt_w(const void* Wl, const void* bl, const void* Wr,
                        const void* Wo, const void* bo,
                        float* wl, float* blf, float* wr, float* wo, float* bof,
                        const int* __restrict__ flags) {
  bool f32m = flags[1] > 1000;
  int i = blockIdx.x * blockDim.x + threadIdx.x;
  if (i < 3 * HD * HD) {
    wl[i] = ldf(Wl, i, f32m);
    wr[i] = ldf(Wr, i, f32m);
  } else {
    int j = i - 3 * HD * HD;
    if (j < 3 * HD) blf[j] = ldf(bl, j, f32m);
    else {
      j -= 3 * HD;
      if (j < HD * OD) wo[j] = ldf(Wo, j, f32m);
      else {
        j -= HD * OD;
        if (j < OD) bof[j] = ldf(bo, j, f32m);
      }
    }
  }
}

__device__ __forceinline__ int edge_at(const void* eidx, long pos, bool i64) {
  return i64 ? (int)((const long long*)eidx)[pos] : ((const int*)eidx)[pos];
}

__global__ void k_deg(const void* __restrict__ eidx, float* __restrict__ rdeg,
                      const int* __restrict__ flags) {
  bool i64 = (flags[0] == 0);
  int e = blockIdx.x * blockDim.x + threadIdx.x;
  if (e < NE) {
    int dst = edge_at(eidx, (long)NE + e, i64);
    atomicAdd(&rdeg[dst], 1.0f);
  }
}

__global__ void k_rdeg(float* __restrict__ rdeg) {
  int i = blockIdx.x * blockDim.x + threadIdx.x;
  if (i < NN) rdeg[i] = 1.0f / fmaxf(rdeg[i], 1.0f);
}

// one wave per edge; lane = feature channel. coalesced gather + coalesced atomic scatter.
__global__ __launch_bounds__(256) void k_scatter(const float* __restrict__ xf,
                                                 const void* __restrict__ eidx,
                                                 float* __restrict__ agg,
                                                 const int* __restrict__ flags) {
  bool i64 = (flags[0] == 0);
  long gid = (long)blockIdx.x * blockDim.x + threadIdx.x;
  int e = (int)(gid >> 6);
  int lane = (int)(gid & 63);
  if (e < NE) {
    int src = edge_at(eidx, e, i64);
    int dst = edge_at(eidx, (long)NE + e, i64);
    atomicAdd(&agg[(long)dst * HD + lane], xf[(long)src * HD + lane]);
  }
}

// fused SAGE layer: x[n] = relu(agg[n]*rdeg[n] @ Wl + bl + x[n] @ Wr), in place.
// one wave per node (grid-stride); weights staged in LDS as f32.
__global__ __launch_bounds__(256) void k_layer(float* __restrict__ xf,
                                               const float* __restrict__ agg,
                                               const float* __restrict__ rdeg,
                                               const float* __restrict__ wl3,
                                               const float* __restrict__ bl3,
                                               const float* __restrict__ wr3,
                                               int layer) {
  __shared__ float sW[2 * HD * HD + HD];
  float* sWl = sW;
  float* sWr = sW + HD * HD;
  float* sbl = sW + 2 * HD * HD;
  const float* wl = wl3 + layer * HD * HD;
  const float* wr = wr3 + layer * HD * HD;
  for (int i = threadIdx.x; i < HD * HD; i += blockDim.x) {
    sWl[i] = wl[i];
    sWr[i] = wr[i];
  }
  if (threadIdx.x < HD) sbl[threadIdx.x] = bl3[layer * HD + threadIdx.x];
  __syncthreads();

  int lane = threadIdx.x & 63;
  int wid = (int)((blockIdx.x * blockDim.x + threadIdx.x) >> 6);
  int nwaves = (int)((gridDim.x * blockDim.x) >> 6);
  for (int n = wid; n < NN; n += nwaves) {
    float rd = rdeg[n];
    float a = agg[(long)n * HD + lane] * rd;
    float xv = xf[(long)n * HD + lane];
    float acc = sbl[lane];
#pragma unroll 16
    for (int k = 0; k < HD; ++k) {
      acc += __shfl(a, k) * sWl[k * HD + lane] + __shfl(xv, k) * sWr[k * HD + lane];
    }
    xf[(long)n * HD + lane] = fmaxf(acc, 0.0f);
  }
}

// final projection 64 -> 16, dual-dtype store per detected mode.
__global__ __launch_bounds__(256) void k_out(const float* __restrict__ xf,
                                             const float* __restrict__ wo,
                                             const float* __restrict__ bo,
                                             void* __restrict__ out,
                                             const int* __restrict__ flags) {
  bool f32m = flags[1] > 1000;
  int gid = blockIdx.x * blockDim.x + threadIdx.x;
  if (gid >= NN * OD) return;
  int n = gid >> 4;
  int o = gid & 15;
  float acc = bo[o];
  const float* row = xf + (long)n * HD;
#pragma unroll
  for (int k = 0; k < HD; ++k) acc += row[k] * wo[k * OD + o];
  if (f32m) ((float*)out)[gid] = acc;
  else ((bf16*)out)[gid] = __float2bfloat16(acc);
}

extern "C" void kernel_launch(void* const* d_in, const int* in_sizes, int n_in,
                              void* d_out, int out_size, void* d_ws, size_t ws_size,
                              hipStream_t stream) {
  const void* x = d_in[0];
  const void* eidx = d_in[1];
  const void* Wl = d_in[2];
  const void* bl = d_in[3];
  const void* Wr = d_in[4];
  const void* Wo = d_in[5];
  const void* bo = d_in[6];

  char* w = (char*)d_ws;
  size_t off = 0;
  int* flags = (int*)(w + off);   off += 256;
  float* xf = (float*)(w + off);  off += (size_t)NN * HD * 4;
  float* agg = (float*)(w + off); off += (size_t)NN * HD * 4;
  float* rdeg = (float*)(w + off); off += (size_t)NN * 4 + 192; // pad to keep 256B align
  float* wl = (float*)(w + off);  off += 3 * HD * HD * 4;
  float* blf = (float*)(w + off); off += 3 * HD * 4;
  float* wr = (float*)(w + off);  off += 3 * HD * HD * 4;
  float* wo = (float*)(w + off);  off += HD * OD * 4;
  float* bof = (float*)(w + off); off += OD * 4;

  hipMemsetAsync(flags, 0, 256, stream);
  hipMemsetAsync(rdeg, 0, (size_t)NN * 4, stream);

  k_detect<<<256, 256, 0, stream>>>((const unsigned int*)eidx, (const unsigned short*)x, flags);
  k_cvt_x<<<(NN * HD + 255) / 256, 256, 0, stream>>>(x, xf, flags);
  k_cvt_w<<<(13520 + 255) / 256, 256, 0, stream>>>(Wl, bl, Wr, Wo, bo, wl, blf, wr, wo, bof, flags);
  k_deg<<<(NE + 255) / 256, 256, 0, stream>>>(eidx, rdeg, flags);
  k_rdeg<<<(NN + 255) / 256, 256, 0, stream>>>(rdeg);

  for (int l = 0; l < 3; ++l) {
    hipMemsetAsync(agg, 0, (size_t)NN * HD * 4, stream);
    k_scatter<<<(int)(((long)NE * 64) / 256), 256, 0, stream>>>(xf, eidx, agg, flags);
    k_layer<<<2048, 256, 0, stream>>>(xf, agg, rdeg, wl, blf, wr, l);
  }

  k_out<<<(NN * OD + 255) / 256, 256, 0, stream>>>(xf, wo, bof, d_out, flags);
}

// Round 2
// 699.536 us; speedup vs baseline: 1.4262x; 1.4262x over previous
//
#include <hip/hip_runtime.h>
#include <hip/hip_bf16.h>

#define NN 50000
#define NE 800000
#define HD 64
#define OD 16

typedef __hip_bfloat16 bf16;

// ---- dtype-robust load: flags[1]>1000 => float tensors are f32, else bf16 ----
__device__ __forceinline__ float ldf(const void* p, long i, bool f32m) {
  return f32m ? ((const float*)p)[i] : __bfloat162float(((const bf16*)p)[i]);
}

// ---- probe: int64-vs-int32 edges (flags[0]), f32-vs-bf16 floats (flags[1]) ----
__global__ void k_detect(const unsigned int* __restrict__ e32,
                         const unsigned short* __restrict__ xu,
                         int* flags) {
  int i = blockIdx.x * blockDim.x + threadIdx.x;
  if (i < 4096) {
    if (e32[2 * i + 1] != 0u) atomicOr(&flags[0], 1);   // nonzero odd word => int32
  }
  if (i < 65536) {
    unsigned short v = xu[i];
    int e = (v >> 7) & 0xFF;
    if (v != 0 && (e < 100 || e > 140)) atomicAdd(&flags[1], 1);  // wild exponent => f32
  }
}

__global__ void k_cvt_x(const void* __restrict__ x, float* __restrict__ xf,
                        const int* __restrict__ flags) {
  bool f32m = flags[1] > 1000;
  int i = blockIdx.x * blockDim.x + threadIdx.x;
  if (i < NN * HD) xf[i] = ldf(x, i, f32m);
}

__global__ void k_cvt_w(const void* Wl, const void* bl, const void* Wr,
                        const void* Wo, const void* bo,
                        float* wl, float* blf, float* wr, float* wo, float* bof,
                        const int* __restrict__ flags) {
  bool f32m = flags[1] > 1000;
  int i = blockIdx.x * blockDim.x + threadIdx.x;
  if (i < 3 * HD * HD) {
    wl[i] = ldf(Wl, i, f32m);
    wr[i] = ldf(Wr, i, f32m);
  } else {
    int j = i - 3 * HD * HD;
    if (j < 3 * HD) blf[j] = ldf(bl, j, f32m);
    else {
      j -= 3 * HD;
      if (j < HD * OD) wo[j] = ldf(Wo, j, f32m);
      else {
        j -= HD * OD;
        if (j < OD) bof[j] = ldf(bo, j, f32m);
      }
    }
  }
}

__device__ __forceinline__ int edge_at(const void* eidx, long pos, bool i64) {
  return i64 ? (int)((const long long*)eidx)[pos] : ((const int*)eidx)[pos];
}

// in-degree count (int)
__global__ void k_count(const void* __restrict__ eidx, int* __restrict__ deg,
                        const int* __restrict__ flags) {
  bool i64 = (flags[0] == 0);
  int e = blockIdx.x * blockDim.x + threadIdx.x;
  if (e < NE) {
    int dst = edge_at(eidx, (long)NE + e, i64);
    atomicAdd(&deg[dst], 1);
  }
}

// single-workgroup exclusive scan of deg[NN] -> rowstart, cursor; also rdeg = 1/max(deg,1)
#define SCAN_T 1024
__global__ __launch_bounds__(SCAN_T) void k_scan(const int* __restrict__ deg,
                                                 int* __restrict__ rowstart,
                                                 int* __restrict__ cursor,
                                                 float* __restrict__ rdeg) {
  __shared__ int part[SCAN_T];
  int t = threadIdx.x;
  const int chunk = (NN + SCAN_T - 1) / SCAN_T;  // 49
  int lo = t * chunk;
  int hi = lo + chunk; if (hi > NN) hi = NN;
  int s = 0;
  for (int i = lo; i < hi; ++i) s += deg[i];
  part[t] = s;
  __syncthreads();
  // Hillis-Steele inclusive scan over 1024 partials
  for (int off = 1; off < SCAN_T; off <<= 1) {
    int v = (t >= off) ? part[t - off] : 0;
    __syncthreads();
    part[t] += v;
    __syncthreads();
  }
  int run = part[t] - s;  // exclusive prefix for this thread's chunk
  for (int i = lo; i < hi; ++i) {
    int d = deg[i];
    rowstart[i] = run;
    cursor[i] = run;
    rdeg[i] = 1.0f / (float)(d > 0 ? d : 1);
    run += d;
  }
}

// fill CSR: csr_src sorted by dst bucket
__global__ void k_fill(const void* __restrict__ eidx, int* __restrict__ cursor,
                       int* __restrict__ csr, const int* __restrict__ flags) {
  bool i64 = (flags[0] == 0);
  int e = blockIdx.x * blockDim.x + threadIdx.x;
  if (e < NE) {
    int src = edge_at(eidx, e, i64);
    int dst = edge_at(eidx, (long)NE + e, i64);
    int pos = atomicAdd(&cursor[dst], 1);
    csr[pos] = src;
  }
}

// fused: agg = mean_{src in N(n)} xin[src]; xout[n] = relu(agg@Wl + bl + xin[n]@Wr)
// one wave per node (grid-stride); lane = feature channel; weights in LDS.
__global__ __launch_bounds__(256) void k_fused(const float* __restrict__ xin,
                                               float* __restrict__ xout,
                                               const int* __restrict__ rowstart,
                                               const int* __restrict__ deg,
                                               const float* __restrict__ rdeg,
                                               const int* __restrict__ csr,
                                               const float* __restrict__ wl3,
                                               const float* __restrict__ bl3,
                                               const float* __restrict__ wr3,
                                               int layer) {
  __shared__ float sW[2 * HD * HD + HD];
  float* sWl = sW;
  float* sWr = sW + HD * HD;
  float* sbl = sW + 2 * HD * HD;
  const float* wl = wl3 + layer * HD * HD;
  const float* wr = wr3 + layer * HD * HD;
  for (int i = threadIdx.x; i < HD * HD; i += blockDim.x) {
    sWl[i] = wl[i];
    sWr[i] = wr[i];
  }
  if (threadIdx.x < HD) sbl[threadIdx.x] = bl3[layer * HD + threadIdx.x];
  __syncthreads();

  int lane = threadIdx.x & 63;
  int wid = (int)((blockIdx.x * blockDim.x + threadIdx.x) >> 6);
  int nwaves = (int)((gridDim.x * blockDim.x) >> 6);
  for (int n = wid; n < NN; n += nwaves) {
    int start = rowstart[n];
    int d = deg[n];
    float acc0 = 0.0f, acc1 = 0.0f;
    for (int base = 0; base < d; base += 64) {
      int cnt = d - base; if (cnt > 64) cnt = 64;
      int myidx = (base + lane < d) ? csr[start + base + lane] : 0;
      int j = 0;
      for (; j + 1 < cnt; j += 2) {
        int s0 = __shfl(myidx, j);
        int s1 = __shfl(myidx, j + 1);
        acc0 += xin[(long)s0 * HD + lane];
        acc1 += xin[(long)s1 * HD + lane];
      }
      if (j < cnt) {
        int s0 = __shfl(myidx, j);
        acc0 += xin[(long)s0 * HD + lane];
      }
    }
    float a = (acc0 + acc1) * rdeg[n];
    float xv = xin[(long)n * HD + lane];
    float r = sbl[lane];
#pragma unroll 16
    for (int k = 0; k < HD; ++k) {
      r += __shfl(a, k) * sWl[k * HD + lane] + __shfl(xv, k) * sWr[k * HD + lane];
    }
    xout[(long)n * HD + lane] = fmaxf(r, 0.0f);
  }
}

// final projection 64 -> 16, dual-dtype store per detected mode.
__global__ __launch_bounds__(256) void k_out(const float* __restrict__ xf,
                                             const float* __restrict__ wo,
                                             const float* __restrict__ bo,
                                             void* __restrict__ out,
                                             const int* __restrict__ flags) {
  bool f32m = flags[1] > 1000;
  int gid = blockIdx.x * blockDim.x + threadIdx.x;
  if (gid >= NN * OD) return;
  int n = gid >> 4;
  int o = gid & 15;
  float acc = bo[o];
  const float* row = xf + (long)n * HD;
#pragma unroll
  for (int k = 0; k < HD; ++k) acc += row[k] * wo[k * OD + o];
  if (f32m) ((float*)out)[gid] = acc;
  else ((bf16*)out)[gid] = __float2bfloat16(acc);
}

extern "C" void kernel_launch(void* const* d_in, const int* in_sizes, int n_in,
                              void* d_out, int out_size, void* d_ws, size_t ws_size,
                              hipStream_t stream) {
  const void* x = d_in[0];
  const void* eidx = d_in[1];
  const void* Wl = d_in[2];
  const void* bl = d_in[3];
  const void* Wr = d_in[4];
  const void* Wo = d_in[5];
  const void* bo = d_in[6];

  char* w = (char*)d_ws;
  size_t off = 0;
  int* flags = (int*)(w + off);     off += 256;
  float* xA = (float*)(w + off);    off += (size_t)NN * HD * 4;
  float* xB = (float*)(w + off);    off += (size_t)NN * HD * 4;
  int* csr = (int*)(w + off);       off += (size_t)NE * 4;
  int* deg = (int*)(w + off);       off += (size_t)NN * 4 + 192;
  int* rowstart = (int*)(w + off);  off += (size_t)NN * 4 + 192;
  int* cursor = (int*)(w + off);    off += (size_t)NN * 4 + 192;
  float* rdeg = (float*)(w + off);  off += (size_t)NN * 4 + 192;
  float* wl = (float*)(w + off);    off += 3 * HD * HD * 4;
  float* blf = (float*)(w + off);   off += 3 * HD * 4;
  float* wr = (float*)(w + off);    off += 3 * HD * HD * 4;
  float* wo = (float*)(w + off);    off += HD * OD * 4;
  float* bof = (float*)(w + off);   off += OD * 4;

  hipMemsetAsync(flags, 0, 256, stream);
  hipMemsetAsync(deg, 0, (size_t)NN * 4, stream);

  k_detect<<<256, 256, 0, stream>>>((const unsigned int*)eidx, (const unsigned short*)x, flags);
  k_cvt_x<<<(NN * HD + 255) / 256, 256, 0, stream>>>(x, xA, flags);
  k_cvt_w<<<(13520 + 255) / 256, 256, 0, stream>>>(Wl, bl, Wr, Wo, bo, wl, blf, wr, wo, bof, flags);

  k_count<<<(NE + 255) / 256, 256, 0, stream>>>(eidx, deg, flags);
  k_scan<<<1, SCAN_T, 0, stream>>>(deg, rowstart, cursor, rdeg);
  k_fill<<<(NE + 255) / 256, 256, 0, stream>>>(eidx, cursor, csr, flags);

  float* bufs[2] = {xA, xB};
  for (int l = 0; l < 3; ++l) {
    k_fused<<<2048, 256, 0, stream>>>(bufs[l & 1], bufs[(l + 1) & 1], rowstart, deg, rdeg,
                                      csr, wl, blf, wr, l);
  }

  k_out<<<(NN * OD + 255) / 256, 256, 0, stream>>>(bufs[1], wo, bof, d_out, flags);
}

// Round 3
// 479.481 us; speedup vs baseline: 2.0807x; 1.4589x over previous
//
#include <hip/hip_runtime.h>
#include <hip/hip_bf16.h>

#define NN 50000
#define NE 800000
#define HD 64
#define OD 16
#define NB 196      // scan blocks: 196*256 = 50176 >= NN

typedef __hip_bfloat16 bf16;

__device__ __forceinline__ float ldf(const void* p, long i, bool f32m) {
  return f32m ? ((const float*)p)[i] : __bfloat162float(((const bf16*)p)[i]);
}

__device__ __forceinline__ float rlf(float v, int l) {
  return __int_as_float(__builtin_amdgcn_readlane(__float_as_int(v), l));
}

// ---- probe: int64-vs-int32 edges (flags[0]), f32-vs-bf16 floats (flags[1]) ----
__global__ void k_detect(const unsigned int* __restrict__ e32,
                         const unsigned short* __restrict__ xu,
                         int* flags) {
  int i = blockIdx.x * blockDim.x + threadIdx.x;
  if (i < 4096) {
    if (e32[2 * i + 1] != 0u) atomicOr(&flags[0], 1);
  }
  if (i < 65536) {
    unsigned short v = xu[i];
    int e = (v >> 7) & 0xFF;
    if (v != 0 && (e < 100 || e > 140)) atomicAdd(&flags[1], 1);
  }
}

__global__ void k_cvt_x(const void* __restrict__ x, float* __restrict__ xf,
                        const int* __restrict__ flags) {
  bool f32m = flags[1] > 1000;
  int i = blockIdx.x * blockDim.x + threadIdx.x;
  if (i < NN * HD) xf[i] = ldf(x, i, f32m);
}

__global__ void k_cvt_w(const void* Wl, const void* bl, const void* Wr,
                        const void* Wo, const void* bo,
                        float* wl, float* blf, float* wr, float* wo, float* bof,
                        const int* __restrict__ flags) {
  bool f32m = flags[1] > 1000;
  int i = blockIdx.x * blockDim.x + threadIdx.x;
  if (i < 3 * HD * HD) {
    wl[i] = ldf(Wl, i, f32m);
    wr[i] = ldf(Wr, i, f32m);
  } else {
    int j = i - 3 * HD * HD;
    if (j < 3 * HD) blf[j] = ldf(bl, j, f32m);
    else {
      j -= 3 * HD;
      if (j < HD * OD) wo[j] = ldf(Wo, j, f32m);
      else {
        j -= HD * OD;
        if (j < OD) bof[j] = ldf(bo, j, f32m);
      }
    }
  }
}

__device__ __forceinline__ int edge_at(const void* eidx, long pos, bool i64) {
  return i64 ? (int)((const long long*)eidx)[pos] : ((const int*)eidx)[pos];
}

__global__ void k_count(const void* __restrict__ eidx, int* __restrict__ deg,
                        const int* __restrict__ flags) {
  bool i64 = (flags[0] == 0);
  int e = blockIdx.x * blockDim.x + threadIdx.x;
  if (e < NE) {
    int dst = edge_at(eidx, (long)NE + e, i64);
    atomicAdd(&deg[dst], 1);
  }
}

// ---- parallel two-level scan (replaces 135us single-WG k_scan) ----
__global__ __launch_bounds__(256) void k_part(const int* __restrict__ deg,
                                              int* __restrict__ bsum) {
  __shared__ int red[256];
  int t = threadIdx.x;
  int i = blockIdx.x * 256 + t;
  red[t] = (i < NN) ? deg[i] : 0;
  __syncthreads();
  for (int off = 128; off > 0; off >>= 1) {
    if (t < off) red[t] += red[t + off];
    __syncthreads();
  }
  if (t == 0) bsum[blockIdx.x] = red[0];
}

__global__ __launch_bounds__(256) void k_scanb(const int* __restrict__ bsum,
                                               int* __restrict__ boff) {
  __shared__ int s[256];
  int t = threadIdx.x;
  int v = (t < NB) ? bsum[t] : 0;
  s[t] = v;
  __syncthreads();
  for (int off = 1; off < 256; off <<= 1) {
    int u = (t >= off) ? s[t - off] : 0;
    __syncthreads();
    s[t] += u;
    __syncthreads();
  }
  if (t < NB) boff[t] = s[t] - v;  // exclusive
}

__global__ __launch_bounds__(256) void k_rowfill(const int* __restrict__ deg,
                                                 const int* __restrict__ boff,
                                                 int* __restrict__ rowstart,
                                                 int* __restrict__ cursor,
                                                 float* __restrict__ rdeg) {
  __shared__ int s[256];
  int t = threadIdx.x;
  int i = blockIdx.x * 256 + t;
  int d = (i < NN) ? deg[i] : 0;
  s[t] = d;
  __syncthreads();
  for (int off = 1; off < 256; off <<= 1) {
    int u = (t >= off) ? s[t - off] : 0;
    __syncthreads();
    s[t] += u;
    __syncthreads();
  }
  if (i < NN) {
    int rs = boff[blockIdx.x] + s[t] - d;  // exclusive prefix
    rowstart[i] = rs;
    cursor[i] = rs;
    rdeg[i] = 1.0f / (float)(d > 0 ? d : 1);
  }
}

__global__ void k_fill(const void* __restrict__ eidx, int* __restrict__ cursor,
                       int* __restrict__ csr, const int* __restrict__ flags) {
  bool i64 = (flags[0] == 0);
  int e = blockIdx.x * blockDim.x + threadIdx.x;
  if (e < NE) {
    int src = edge_at(eidx, e, i64);
    int dst = edge_at(eidx, (long)NE + e, i64);
    int pos = atomicAdd(&cursor[dst], 1);
    csr[pos] = src;
  }
}

// fused SAGE layer, 4 nodes per wave:
//   agg = mean_{src} xin[src];  xout = relu(agg@Wl + bl + xin@Wr)
// lane = feature; broadcasts via readlane (VALU) not shfl (DS pipe);
// LDS weights interleaved sW[k*128 + f] (Wl) / sW[k*128+64+f] (Wr) so each
// weight read is amortized over 4 nodes and the pair merges to ds_read2_b32.
#define NG 4
__global__ __launch_bounds__(256) void k_fused(const float* __restrict__ xin,
                                               float* __restrict__ xout,
                                               const int* __restrict__ rowstart,
                                               const int* __restrict__ deg,
                                               const float* __restrict__ rdeg,
                                               const int* __restrict__ csr,
                                               const float* __restrict__ wl3,
                                               const float* __restrict__ bl3,
                                               const float* __restrict__ wr3,
                                               int layer) {
  __shared__ float sW[HD * 2 * HD];
  __shared__ float sbl[HD];
  const float* wl = wl3 + layer * HD * HD;
  const float* wr = wr3 + layer * HD * HD;
  for (int i = threadIdx.x; i < HD * HD; i += blockDim.x) {
    int k = i >> 6, f = i & 63;
    sW[k * 128 + f] = wl[i];
    sW[k * 128 + 64 + f] = wr[i];
  }
  if (threadIdx.x < HD) sbl[threadIdx.x] = bl3[layer * HD + threadIdx.x];
  __syncthreads();

  int lane = threadIdx.x & 63;
  int wid = (int)((blockIdx.x * blockDim.x + threadIdx.x) >> 6);
  int nwaves = (int)((gridDim.x * blockDim.x) >> 6);

  for (int nb = wid * NG; nb < NN; nb += nwaves * NG) {
    float a[NG], xv[NG], r[NG];
#pragma unroll
    for (int g = 0; g < NG; ++g) {
      int n = nb + g;
      if (n < NN) {
        int start = rowstart[n];
        int d = deg[n];
        float acc0 = 0.0f, acc1 = 0.0f;
        for (int base = 0; base < d; base += 64) {
          int cnt = d - base; if (cnt > 64) cnt = 64;
          int myidx = (base + lane < d) ? csr[start + base + lane] : 0;
          int j = 0;
          for (; j + 1 < cnt; j += 2) {
            int s0 = __builtin_amdgcn_readlane(myidx, j);
            int s1 = __builtin_amdgcn_readlane(myidx, j + 1);
            acc0 += xin[(long)s0 * HD + lane];
            acc1 += xin[(long)s1 * HD + lane];
          }
          if (j < cnt) {
            int s0 = __builtin_amdgcn_readlane(myidx, j);
            acc0 += xin[(long)s0 * HD + lane];
          }
        }
        a[g] = (acc0 + acc1) * rdeg[n];
        xv[g] = xin[(long)n * HD + lane];
      } else {
        a[g] = 0.0f; xv[g] = 0.0f;
      }
      r[g] = sbl[lane];
    }

#pragma unroll 16
    for (int k = 0; k < HD; ++k) {
      float wlv = sW[k * 128 + lane];
      float wrv = sW[k * 128 + 64 + lane];
#pragma unroll
      for (int g = 0; g < NG; ++g) {
        r[g] += rlf(a[g], k) * wlv + rlf(xv[g], k) * wrv;
      }
    }

#pragma unroll
    for (int g = 0; g < NG; ++g) {
      int n = nb + g;
      if (n < NN) xout[(long)n * HD + lane] = fmaxf(r[g], 0.0f);
    }
  }
}

__global__ __launch_bounds__(256) void k_out(const float* __restrict__ xf,
                                             const float* __restrict__ wo,
                                             const float* __restrict__ bo,
                                             void* __restrict__ out,
                                             const int* __restrict__ flags) {
  bool f32m = flags[1] > 1000;
  int gid = blockIdx.x * blockDim.x + threadIdx.x;
  if (gid >= NN * OD) return;
  int n = gid >> 4;
  int o = gid & 15;
  float acc = bo[o];
  const float* row = xf + (long)n * HD;
#pragma unroll
  for (int k = 0; k < HD; ++k) acc += row[k] * wo[k * OD + o];
  if (f32m) ((float*)out)[gid] = acc;
  else ((bf16*)out)[gid] = __float2bfloat16(acc);
}

extern "C" void kernel_launch(void* const* d_in, const int* in_sizes, int n_in,
                              void* d_out, int out_size, void* d_ws, size_t ws_size,
                              hipStream_t stream) {
  const void* x = d_in[0];
  const void* eidx = d_in[1];
  const void* Wl = d_in[2];
  const void* bl = d_in[3];
  const void* Wr = d_in[4];
  const void* Wo = d_in[5];
  const void* bo = d_in[6];

  char* w = (char*)d_ws;
  size_t off = 0;
  int* flags = (int*)(w + off);     off += 256;
  float* xA = (float*)(w + off);    off += (size_t)NN * HD * 4;
  float* xB = (float*)(w + off);    off += (size_t)NN * HD * 4;
  int* csr = (int*)(w + off);       off += (size_t)NE * 4;
  int* deg = (int*)(w + off);       off += (size_t)NN * 4 + 192;
  int* rowstart = (int*)(w + off);  off += (size_t)NN * 4 + 192;
  int* cursor = (int*)(w + off);    off += (size_t)NN * 4 + 192;
  float* rdeg = (float*)(w + off);  off += (size_t)NN * 4 + 192;
  int* bsum = (int*)(w + off);      off += 256 * 4;
  int* boff = (int*)(w + off);      off += 256 * 4;
  float* wl = (float*)(w + off);    off += 3 * HD * HD * 4;
  float* blf = (float*)(w + off);   off += 3 * HD * 4;
  float* wr = (float*)(w + off);    off += 3 * HD * HD * 4;
  float* wo = (float*)(w + off);    off += HD * OD * 4;
  float* bof = (float*)(w + off);   off += OD * 4;

  hipMemsetAsync(flags, 0, 256, stream);
  hipMemsetAsync(deg, 0, (size_t)NN * 4, stream);

  k_detect<<<256, 256, 0, stream>>>((const unsigned int*)eidx, (const unsigned short*)x, flags);
  k_cvt_x<<<(NN * HD + 255) / 256, 256, 0, stream>>>(x, xA, flags);
  k_cvt_w<<<(13520 + 255) / 256, 256, 0, stream>>>(Wl, bl, Wr, Wo, bo, wl, blf, wr, wo, bof, flags);

  k_count<<<(NE + 255) / 256, 256, 0, stream>>>(eidx, deg, flags);
  k_part<<<NB, 256, 0, stream>>>(deg, bsum);
  k_scanb<<<1, 256, 0, stream>>>(bsum, boff);
  k_rowfill<<<NB, 256, 0, stream>>>(deg, boff, rowstart, cursor, rdeg);
  k_fill<<<(NE + 255) / 256, 256, 0, stream>>>(eidx, cursor, csr, flags);

  float* bufs[2] = {xA, xB};
  for (int l = 0; l < 3; ++l) {
    k_fused<<<2048, 256, 0, stream>>>(bufs[l & 1], bufs[(l + 1) & 1], rowstart, deg, rdeg,
                                      csr, wl, blf, wr, l);
  }

  k_out<<<(NN * OD + 255) / 256, 256, 0, stream>>>(bufs[1], wo, bof, d_out, flags);
}

// Round 4
// 353.444 us; speedup vs baseline: 2.8227x; 1.3566x over previous
//
#include <hip/hip_runtime.h>
#include <hip/hip_bf16.h>

#define NN 50000
#define NE 800000
#define HD 64
#define OD 16
#define NB 196      // 196*256 = 50176 >= NN

typedef unsigned short u16;
typedef unsigned int u32;

__device__ __forceinline__ float bf2f(u16 v) { return __uint_as_float(((u32)v) << 16); }
__device__ __forceinline__ u16 f2bf(float f) {
  __hip_bfloat16 h = __float2bfloat16(f);
  return *reinterpret_cast<u16*>(&h);
}
__device__ __forceinline__ float ldf(const void* p, long i, bool f32m) {
  return f32m ? ((const float*)p)[i] : bf2f(((const u16*)p)[i]);
}
__device__ __forceinline__ float rlf(float v, int l) {
  return __int_as_float(__builtin_amdgcn_readlane(__float_as_int(v), l));
}
__device__ __forceinline__ int edge_at(const void* eidx, long pos, bool i64) {
  return i64 ? (int)((const long long*)eidx)[pos] : ((const int*)eidx)[pos];
}

// ---- probe: int64-vs-int32 edges (flags[0]), f32-vs-bf16 floats (flags[1]) ----
__global__ void k_detect(const u32* __restrict__ e32, const u16* __restrict__ xu,
                         int* flags) {
  int i = blockIdx.x * blockDim.x + threadIdx.x;
  if (i < 4096) {
    if (e32[2 * i + 1] != 0u) atomicOr(&flags[0], 1);
  }
  if (i < 65536) {
    u16 v = xu[i];
    int e = (v >> 7) & 0xFF;
    if (v != 0 && (e < 100 || e > 140)) atomicAdd(&flags[1], 1);
  }
}

// fused: degree count + (f32 mode only) x->bf16 convert + weight pack/convert
// grid: 3125*256 = 800000 threads exactly (== NE == NN*HD/4)
__global__ __launch_bounds__(256) void k_prep(
    const void* __restrict__ x, const void* __restrict__ eidx,
    const void* __restrict__ Wl, const void* __restrict__ bl,
    const void* __restrict__ Wr, const void* __restrict__ Wo,
    const void* __restrict__ bo,
    int* __restrict__ deg, u16* __restrict__ xA, u32* __restrict__ wpk,
    float* __restrict__ blf, float* __restrict__ wof, float* __restrict__ bof,
    const int* __restrict__ flags) {
  bool f32m = flags[1] > 1000;
  bool i64 = (flags[0] == 0);
  int i = blockIdx.x * blockDim.x + threadIdx.x;
  if (i < NE) {
    int dst = edge_at(eidx, (long)NE + i, i64);
    atomicAdd(&deg[dst], 1);
  }
  if (f32m) {  // convert x rows to bf16 (bf16 mode reads the input buffer directly)
    float4 v = ((const float4*)x)[i];
    u32 lo = (u32)f2bf(v.x) | ((u32)f2bf(v.y) << 16);
    u32 hi = (u32)f2bf(v.z) | ((u32)f2bf(v.w) << 16);
    ((u32*)xA)[2 * i] = lo;
    ((u32*)xA)[2 * i + 1] = hi;
  }
  if (i < 3 * HD * HD) {  // pack (Wl,Wr) as bf16 pair
    u16 wl = f2bf(ldf(Wl, i, f32m));
    u16 wr = f2bf(ldf(Wr, i, f32m));
    wpk[i] = (u32)wl | ((u32)wr << 16);
  }
  if (i < 3 * HD) blf[i] = ldf(bl, i, f32m);
  if (i < HD * OD) wof[i] = ldf(Wo, i, f32m);
  if (i < OD) bof[i] = ldf(bo, i, f32m);
}

// block partial sums + last-block scans the 196 partials (fused, 1 dispatch)
__global__ __launch_bounds__(256) void k_scan2(const int* __restrict__ deg,
                                               int* __restrict__ bsum,
                                               int* __restrict__ boff,
                                               int* __restrict__ done) {
  __shared__ int red[256];
  __shared__ int isLast;
  int t = threadIdx.x;
  int i = blockIdx.x * 256 + t;
  red[t] = (i < NN) ? deg[i] : 0;
  __syncthreads();
  for (int off = 128; off > 0; off >>= 1) {
    if (t < off) red[t] += red[t + off];
    __syncthreads();
  }
  if (t == 0) {
    __hip_atomic_store(&bsum[blockIdx.x], red[0], __ATOMIC_RELEASE, __HIP_MEMORY_SCOPE_AGENT);
    __threadfence();
    int p = atomicAdd(done, 1);
    isLast = (p == NB - 1) ? 1 : 0;
  }
  __syncthreads();
  if (isLast) {
    __threadfence();
    int v = 0;
    if (t < NB) v = __hip_atomic_load(&bsum[t], __ATOMIC_ACQUIRE, __HIP_MEMORY_SCOPE_AGENT);
    red[t] = v;
    __syncthreads();
    for (int off = 1; off < 256; off <<= 1) {
      int u = (t >= off) ? red[t - off] : 0;
      __syncthreads();
      red[t] += u;
      __syncthreads();
    }
    if (t < NB) boff[t] = red[t] - v;  // exclusive
  }
}

__global__ __launch_bounds__(256) void k_rowfill(const int* __restrict__ deg,
                                                 const int* __restrict__ boff,
                                                 int* __restrict__ rowstart,
                                                 int* __restrict__ cursor,
                                                 float* __restrict__ rdeg) {
  __shared__ int s[256];
  int t = threadIdx.x;
  int i = blockIdx.x * 256 + t;
  int d = (i < NN) ? deg[i] : 0;
  s[t] = d;
  __syncthreads();
  for (int off = 1; off < 256; off <<= 1) {
    int u = (t >= off) ? s[t - off] : 0;
    __syncthreads();
    s[t] += u;
    __syncthreads();
  }
  if (i < NN) {
    int rs = boff[blockIdx.x] + s[t] - d;
    rowstart[i] = rs;
    cursor[i] = rs;
    rdeg[i] = 1.0f / (float)(d > 0 ? d : 1);
  }
}

__global__ __launch_bounds__(256) void k_fill(const void* __restrict__ eidx,
                                              int* __restrict__ cursor,
                                              int* __restrict__ csr,
                                              const int* __restrict__ flags) {
  bool i64 = (flags[0] == 0);
  int e = blockIdx.x * blockDim.x + threadIdx.x;
  if (e < NE) {
    int src = edge_at(eidx, e, i64);
    int dst = edge_at(eidx, (long)NE + e, i64);
    int pos = atomicAdd(&cursor[dst], 1);
    csr[pos] = src;
  }
}

// fused SAGE layer on bf16 x, 4 nodes/wave, uniform gather loops,
// packed bf16 (Wl,Wr) in 16.6 KB LDS -> 8 blocks/CU.
__global__ __launch_bounds__(256, 8) void k_fused(
    const u16* __restrict__ xin_bf, const u16* __restrict__ xin_f32m,
    u16* __restrict__ xout,
    const int* __restrict__ rowstart, const int* __restrict__ deg,
    const float* __restrict__ rdeg, const int* __restrict__ csr,
    const u32* __restrict__ wpk, const float* __restrict__ bl3,
    int layer, const int* __restrict__ flags) {
  __shared__ u32 sW[HD * HD];
  __shared__ float sbl[HD];
  const u32* wp = wpk + layer * HD * HD;
  for (int i = threadIdx.x; i < HD * HD; i += 256) sW[i] = wp[i];
  if (threadIdx.x < HD) sbl[threadIdx.x] = bl3[layer * HD + threadIdx.x];
  const u16* xin = (flags[1] > 1000) ? xin_f32m : xin_bf;
  __syncthreads();

  int lane = threadIdx.x & 63;
  int wid = (int)((blockIdx.x * 256 + threadIdx.x) >> 6);
  int nwaves = (int)((gridDim.x * 256) >> 6);

  for (int nb = wid * 4; nb < NN; nb += nwaves * 4) {  // NN % 4 == 0: no partial groups
    float a[4], xv[4];
#pragma unroll
    for (int g = 0; g < 4; ++g) {
      int n = nb + g;
      int start = __builtin_amdgcn_readfirstlane(rowstart[n]);
      int d = __builtin_amdgcn_readfirstlane(deg[n]);
      float c0 = 0.f, c1 = 0.f, c2 = 0.f, c3 = 0.f;
      for (int base = 0; base < d; base += 64) {
        int cnt = d - base;
        if (cnt > 64) cnt = 64;
        int idx = (base + lane < d) ? csr[start + base + lane] : 0;
        int j = 0;
        for (; j + 3 < cnt; j += 4) {
          int s0 = __builtin_amdgcn_readlane(idx, j);
          int s1 = __builtin_amdgcn_readlane(idx, j + 1);
          int s2 = __builtin_amdgcn_readlane(idx, j + 2);
          int s3 = __builtin_amdgcn_readlane(idx, j + 3);
          c0 += bf2f(xin[(long)s0 * HD + lane]);
          c1 += bf2f(xin[(long)s1 * HD + lane]);
          c2 += bf2f(xin[(long)s2 * HD + lane]);
          c3 += bf2f(xin[(long)s3 * HD + lane]);
        }
        for (; j < cnt; ++j) {
          int s0 = __builtin_amdgcn_readlane(idx, j);
          c0 += bf2f(xin[(long)s0 * HD + lane]);
        }
      }
      a[g] = (c0 + c1 + c2 + c3) * rdeg[n];
      xv[g] = bf2f(xin[(long)n * HD + lane]);
    }

    float r0 = sbl[lane], r1 = r0, r2 = r0, r3 = r0;
#pragma unroll 16
    for (int k = 0; k < HD; ++k) {
      u32 w = sW[k * HD + lane];
      float wlv = __uint_as_float(w << 16);
      float wrv = __uint_as_float(w & 0xffff0000u);
      r0 += rlf(a[0], k) * wlv + rlf(xv[0], k) * wrv;
      r1 += rlf(a[1], k) * wlv + rlf(xv[1], k) * wrv;
      r2 += rlf(a[2], k) * wlv + rlf(xv[2], k) * wrv;
      r3 += rlf(a[3], k) * wlv + rlf(xv[3], k) * wrv;
    }
    xout[(long)(nb + 0) * HD + lane] = f2bf(fmaxf(r0, 0.f));
    xout[(long)(nb + 1) * HD + lane] = f2bf(fmaxf(r1, 0.f));
    xout[(long)(nb + 2) * HD + lane] = f2bf(fmaxf(r2, 0.f));
    xout[(long)(nb + 3) * HD + lane] = f2bf(fmaxf(r3, 0.f));
  }
}

// final 64->16 projection from bf16 x
__global__ __launch_bounds__(256) void k_out(const u16* __restrict__ xf,
                                             const float* __restrict__ wof,
                                             const float* __restrict__ bof,
                                             void* __restrict__ out,
                                             const int* __restrict__ flags) {
  bool f32m = flags[1] > 1000;
  int gid = blockIdx.x * blockDim.x + threadIdx.x;
  if (gid >= NN * OD) return;
  int n = gid >> 4;
  int o = gid & 15;
  float acc = bof[o];
  const u32* row = (const u32*)(xf + (long)n * HD);
#pragma unroll
  for (int kk = 0; kk < 32; ++kk) {
    u32 p = row[kk];
    acc += __uint_as_float(p << 16) * wof[(2 * kk) * OD + o] +
           __uint_as_float(p & 0xffff0000u) * wof[(2 * kk + 1) * OD + o];
  }
  if (f32m) ((float*)out)[gid] = acc;
  else ((u16*)out)[gid] = f2bf(acc);
}

extern "C" void kernel_launch(void* const* d_in, const int* in_sizes, int n_in,
                              void* d_out, int out_size, void* d_ws, size_t ws_size,
                              hipStream_t stream) {
  const void* x = d_in[0];
  const void* eidx = d_in[1];
  const void* Wl = d_in[2];
  const void* bl = d_in[3];
  const void* Wr = d_in[4];
  const void* Wo = d_in[5];
  const void* bo = d_in[6];

  char* w = (char*)d_ws;
  size_t off = 0;
  int* flags = (int*)(w + off);     off += 256;           // flags[0],flags[1],flags[2]=done
  int* deg = (int*)(w + off);       off += (size_t)NN * 4 + 192;  // contiguous w/ flags for 1 memset
  size_t memset_bytes = off;
  int* rowstart = (int*)(w + off);  off += (size_t)NN * 4 + 192;
  int* cursor = (int*)(w + off);    off += (size_t)NN * 4 + 192;
  float* rdeg = (float*)(w + off);  off += (size_t)NN * 4 + 192;
  int* bsum = (int*)(w + off);      off += 256 * 4;
  int* boff = (int*)(w + off);      off += 256 * 4;
  u32* wpk = (u32*)(w + off);       off += 3 * HD * HD * 4;
  float* blf = (float*)(w + off);   off += 3 * HD * 4;
  float* wof = (float*)(w + off);   off += HD * OD * 4;
  float* bof = (float*)(w + off);   off += 256;
  int* csr = (int*)(w + off);       off += (size_t)NE * 4;
  u16* xA = (u16*)(w + off);        off += (size_t)NN * HD * 2;
  u16* xB = (u16*)(w + off);        off += (size_t)NN * HD * 2;
  u16* xC = (u16*)(w + off);        off += (size_t)NN * HD * 2;

  hipMemsetAsync(flags, 0, memset_bytes, stream);

  k_detect<<<256, 256, 0, stream>>>((const u32*)eidx, (const u16*)x, flags);
  k_prep<<<3125, 256, 0, stream>>>(x, eidx, Wl, bl, Wr, Wo, bo, deg, xA, wpk, blf, wof, bof, flags);
  k_scan2<<<NB, 256, 0, stream>>>(deg, bsum, boff, &flags[2]);
  k_rowfill<<<NB, 256, 0, stream>>>(deg, boff, rowstart, cursor, rdeg);
  k_fill<<<3125, 256, 0, stream>>>(eidx, cursor, csr, flags);

  // layer 0: input is original x (bf16 mode) or converted xA (f32 mode) -> xB
  k_fused<<<2048, 256, 0, stream>>>((const u16*)x, xA, xB, rowstart, deg, rdeg, csr,
                                    wpk, blf, 0, flags);
  // layer 1: xB -> xC
  k_fused<<<2048, 256, 0, stream>>>(xB, xB, xC, rowstart, deg, rdeg, csr,
                                    wpk, blf, 1, flags);
  // layer 2: xC -> xB
  k_fused<<<2048, 256, 0, stream>>>(xC, xC, xB, rowstart, deg, rdeg, csr,
                                    wpk, blf, 2, flags);

  k_out<<<3125, 256, 0, stream>>>(xB, wof, bof, d_out, flags);
}

// Round 5
// 344.784 us; speedup vs baseline: 2.8936x; 1.0251x over previous
//
#include <hip/hip_runtime.h>
#include <hip/hip_bf16.h>

#define NN 50000
#define NE 800000
#define HD 64
#define OD 16
#define NB 196        // 196*256 = 50176 >= NN
#define TILES 3125    // NN/16
#define FBLK 782      // ceil(TILES/4)

typedef unsigned short u16;
typedef unsigned int u32;
typedef __attribute__((ext_vector_type(8))) short short8;
typedef __attribute__((ext_vector_type(4))) float f32x4;

__device__ __forceinline__ float bf2f(u16 v) { return __uint_as_float(((u32)v) << 16); }
__device__ __forceinline__ u16 f2bf(float f) {
  __hip_bfloat16 h = __float2bfloat16(f);
  return *reinterpret_cast<u16*>(&h);
}
__device__ __forceinline__ float ldf(const void* p, long i, bool f32m) {
  return f32m ? ((const float*)p)[i] : bf2f(((const u16*)p)[i]);
}
__device__ __forceinline__ int edge_at(const void* eidx, long pos, bool i64) {
  return i64 ? (int)((const long long*)eidx)[pos] : ((const int*)eidx)[pos];
}

// ---- probe: int64-vs-int32 edges (flags[0]), f32-vs-bf16 floats (flags[1]) ----
__global__ void k_detect(const u32* __restrict__ e32, const u16* __restrict__ xu,
                         int* flags) {
  int i = blockIdx.x * blockDim.x + threadIdx.x;
  if (i < 4096) {
    if (e32[2 * i + 1] != 0u) atomicOr(&flags[0], 1);
  }
  if (i < 65536) {
    u16 v = xu[i];
    int e = (v >> 7) & 0xFF;
    if (v != 0 && (e < 100 || e > 140)) atomicAdd(&flags[1], 1);
  }
}

// degree count + (f32 mode) x->bf16 + B-fragment pre-arrangement for MFMA.
// grid: 3125*256 = 800000 == NE == NN*HD/4
// wfrag[l][f][lane][j], f=(s,c): k=32s+(lane>>4)*8+j, n=16c+(lane&15);
//   val = k<64 ? Wl[l][k][n] : Wr[l][k-64][n]
// pfrag[s][lane][j]: k=32s+(lane>>4)*8+j, n=lane&15; val = Wo[k][n]
__global__ __launch_bounds__(256) void k_prep(
    const void* __restrict__ x, const void* __restrict__ eidx,
    const void* __restrict__ Wl, const void* __restrict__ bl,
    const void* __restrict__ Wr, const void* __restrict__ Wo,
    const void* __restrict__ bo,
    int* __restrict__ deg, u16* __restrict__ xA,
    u16* __restrict__ wfrag, u16* __restrict__ pfrag,
    float* __restrict__ blf, float* __restrict__ bof,
    const int* __restrict__ flags) {
  bool f32m = flags[1] > 1000;
  bool i64 = (flags[0] == 0);
  int i = blockIdx.x * blockDim.x + threadIdx.x;
  if (i < NE) {
    int dst = edge_at(eidx, (long)NE + i, i64);
    atomicAdd(&deg[dst], 1);
  }
  if (f32m) {
    float4 v = ((const float4*)x)[i];
    u32 lo = (u32)f2bf(v.x) | ((u32)f2bf(v.y) << 16);
    u32 hi = (u32)f2bf(v.z) | ((u32)f2bf(v.w) << 16);
    ((u32*)xA)[2 * i] = lo;
    ((u32*)xA)[2 * i + 1] = hi;
  }
  if (i < 3 * 16 * 64 * 8) {  // 24576 weight-frag elements
    int j = i & 7, lane = (i >> 3) & 63, f = (i >> 9) & 15, l = i >> 13;
    int s = f >> 2, c = f & 3;
    int k = 32 * s + ((lane >> 4) << 3) + j;
    int n = (c << 4) + (lane & 15);
    long base = (long)l * HD * HD;
    float v = (k < HD) ? ldf(Wl, base + (long)k * HD + n, f32m)
                       : ldf(Wr, base + (long)(k - HD) * HD + n, f32m);
    wfrag[i] = f2bf(v);
  }
  if (i < 2 * 64 * 8) {  // 1024 proj-frag elements
    int j = i & 7, lane = (i >> 3) & 63, s = i >> 9;
    int k = 32 * s + ((lane >> 4) << 3) + j;
    int n = lane & 15;
    pfrag[i] = f2bf(ldf(Wo, (long)k * OD + n, f32m));
  }
  if (i < 3 * HD) blf[i] = ldf(bl, i, f32m);
  if (i < OD) bof[i] = ldf(bo, i, f32m);
}

// single-pass: block-local scan + publish partial + spin + rowstart/cursor/rdeg
// grid = NB = 196 blocks <= 256 CUs -> all co-resident, spin is safe.
__global__ __launch_bounds__(256) void k_scanrow(const int* __restrict__ deg,
                                                 int* __restrict__ bsum,
                                                 int* __restrict__ done,
                                                 int* __restrict__ rowstart,
                                                 int* __restrict__ cursor,
                                                 float* __restrict__ rdeg) {
  __shared__ int s[256];
  __shared__ int red[256];
  int t = threadIdx.x, b = blockIdx.x;
  int i = b * 256 + t;
  int d = (i < NN) ? deg[i] : 0;
  s[t] = d;
  __syncthreads();
  for (int off = 1; off < 256; off <<= 1) {
    int u = (t >= off) ? s[t - off] : 0;
    __syncthreads();
    s[t] += u;
    __syncthreads();
  }
  if (t == 0) {
    __hip_atomic_store(&bsum[b], s[255], __ATOMIC_RELEASE, __HIP_MEMORY_SCOPE_AGENT);
    __hip_atomic_fetch_add(done, 1, __ATOMIC_ACQ_REL, __HIP_MEMORY_SCOPE_AGENT);
    while (__hip_atomic_load(done, __ATOMIC_ACQUIRE, __HIP_MEMORY_SCOPE_AGENT) < NB)
      __builtin_amdgcn_s_sleep(8);
  }
  __syncthreads();
  // boff = sum of bsum[0..b)
  int v = (t < b) ? __hip_atomic_load(&bsum[t], __ATOMIC_RELAXED, __HIP_MEMORY_SCOPE_AGENT) : 0;
  red[t] = v;
  __syncthreads();
  for (int off = 128; off > 0; off >>= 1) {
    if (t < off) red[t] += red[t + off];
    __syncthreads();
  }
  if (i < NN) {
    int rs = red[0] + s[t] - d;
    rowstart[i] = rs;
    cursor[i] = rs;
    rdeg[i] = 1.0f / (float)(d > 0 ? d : 1);
  }
}

__global__ __launch_bounds__(256) void k_fill(const void* __restrict__ eidx,
                                              int* __restrict__ cursor,
                                              int* __restrict__ csr,
                                              const int* __restrict__ flags) {
  bool i64 = (flags[0] == 0);
  int e = blockIdx.x * blockDim.x + threadIdx.x;
  if (e < NE) {
    int src = edge_at(eidx, e, i64);
    int dst = edge_at(eidx, (long)NE + e, i64);
    int pos = atomicAdd(&cursor[dst], 1);
    csr[pos] = src;
  }
}

// fused SAGE layer: gather-mean (VALU/VMEM) + MFMA GEMM.
// 16 nodes per wave; A=[agg|x] K=128 via 4x mfma_f32_16x16x32_bf16 per col-tile.
// doProj: layer-2 epilogue computes out = relu_tile @ Wo + bo directly.
#define AST 72  // padded A/C row stride in u16 (144 B: 16B-aligned, low conflict)
__global__ __launch_bounds__(256, 4) void k_fused(
    const u16* __restrict__ xin_bf, const u16* __restrict__ xin_f32m,
    u16* __restrict__ xout,
    const int* __restrict__ rowstart, const int* __restrict__ deg,
    const float* __restrict__ rdeg, const int* __restrict__ csr,
    const u16* __restrict__ wfrag, const u16* __restrict__ pfrag,
    const float* __restrict__ bl3, const float* __restrict__ bof,
    void* __restrict__ outp, int layer, int doProj,
    const int* __restrict__ flags) {
  __shared__ __align__(16) u16 sB[16 * 64 * 8];   // 16 KB weight frags
  __shared__ __align__(16) u16 sBp[2 * 64 * 8];   // 2 KB proj frags
  __shared__ __align__(16) u16 sA[4][16 * AST];   // per-wave agg/C staging
  __shared__ float sbl[HD];
  __shared__ float sbo[OD];
  {
    const u32* ws = (const u32*)(wfrag + (long)layer * 16 * 64 * 8);
    u32* sb = (u32*)sB;
    for (int i = threadIdx.x; i < 4096; i += 256) sb[i] = ws[i];
    if (doProj) {
      const u32* ps = (const u32*)pfrag;
      u32* sp = (u32*)sBp;
      for (int i = threadIdx.x; i < 512; i += 256) sp[i] = ps[i];
    }
  }
  if (threadIdx.x < HD) sbl[threadIdx.x] = bl3[layer * HD + threadIdx.x];
  if (threadIdx.x < OD) sbo[threadIdx.x] = bof[threadIdx.x];
  bool f32m = flags[1] > 1000;
  const u16* xin = f32m ? xin_f32m : xin_bf;
  __syncthreads();

  int lane = threadIdx.x & 63;
  int w = threadIdx.x >> 6;
  int wid = blockIdx.x * 4 + w;
  if (wid >= TILES) return;
  int nb = wid * 16;
  int quad = lane >> 4;
  int m16 = lane & 15;
  u16* aw = &sA[w][0];

  // ---- gather-mean 16 nodes (lane = feature) ----
  for (int g = 0; g < 16; ++g) {
    int n = nb + g;
    int start = __builtin_amdgcn_readfirstlane(rowstart[n]);
    int d = __builtin_amdgcn_readfirstlane(deg[n]);
    float c0 = 0.f, c1 = 0.f, c2 = 0.f, c3 = 0.f;
    for (int base = 0; base < d; base += 64) {
      int cnt = d - base;
      if (cnt > 64) cnt = 64;
      int idx = (base + lane < d) ? csr[start + base + lane] : 0;
      int j = 0;
      for (; j + 3 < cnt; j += 4) {
        int s0 = __builtin_amdgcn_readlane(idx, j);
        int s1 = __builtin_amdgcn_readlane(idx, j + 1);
        int s2 = __builtin_amdgcn_readlane(idx, j + 2);
        int s3 = __builtin_amdgcn_readlane(idx, j + 3);
        c0 += bf2f(xin[(long)s0 * HD + lane]);
        c1 += bf2f(xin[(long)s1 * HD + lane]);
        c2 += bf2f(xin[(long)s2 * HD + lane]);
        c3 += bf2f(xin[(long)s3 * HD + lane]);
      }
      for (; j < cnt; ++j) {
        int s0 = __builtin_amdgcn_readlane(idx, j);
        c0 += bf2f(xin[(long)s0 * HD + lane]);
      }
    }
    float a = (c0 + c1 + c2 + c3) * rdeg[n];
    aw[g * AST + lane] = f2bf(a);  // A-staging row g
  }

  // ---- A fragments: agg from LDS, x rows straight from global ----
  short8 a0 = *(const short8*)(aw + m16 * AST + quad * 8);        // k 0..31
  short8 a1 = *(const short8*)(aw + m16 * AST + 32 + quad * 8);   // k 32..63
  const u16* xrow = xin + (long)(nb + m16) * HD;
  short8 x2 = *(const short8*)(xrow + quad * 8);                  // k 64..95
  short8 x3 = *(const short8*)(xrow + 32 + quad * 8);             // k 96..127

  // ---- GEMM: 4 col-tiles x 4 k-steps; bias in accumulator init ----
  f32x4 acc[4];
#pragma unroll
  for (int c = 0; c < 4; ++c) {
    float b = sbl[c * 16 + m16];
    acc[c] = (f32x4){b, b, b, b};
  }
  const short8* bp = (const short8*)sB;
#pragma unroll
  for (int c = 0; c < 4; ++c) {
    short8 b0 = bp[(0 * 4 + c) * 64 + lane];
    short8 b1 = bp[(1 * 4 + c) * 64 + lane];
    short8 b2 = bp[(2 * 4 + c) * 64 + lane];
    short8 b3 = bp[(3 * 4 + c) * 64 + lane];
    acc[c] = __builtin_amdgcn_mfma_f32_16x16x32_bf16(a0, b0, acc[c], 0, 0, 0);
    acc[c] = __builtin_amdgcn_mfma_f32_16x16x32_bf16(a1, b1, acc[c], 0, 0, 0);
    acc[c] = __builtin_amdgcn_mfma_f32_16x16x32_bf16(x2, b2, acc[c], 0, 0, 0);
    acc[c] = __builtin_amdgcn_mfma_f32_16x16x32_bf16(x3, b3, acc[c], 0, 0, 0);
  }

  // ---- relu -> C staging (reuse aw; all its reads completed) ----
#pragma unroll
  for (int c = 0; c < 4; ++c)
#pragma unroll
    for (int r = 0; r < 4; ++r) {
      float v = fmaxf(acc[c][r], 0.f);
      aw[(quad * 4 + r) * AST + c * 16 + m16] = f2bf(v);
    }

  if (!doProj) {
    // coalesced store: lane covers row=lane>>2, 32B chunk=lane&3
    int row = lane >> 2, ch = lane & 3;
    const short8* cp = (const short8*)(aw + row * AST + ch * 16);
    short8 v0 = cp[0], v1 = cp[1];
    short8* op = (short8*)(xout + (long)(nb + row) * HD + ch * 16);
    op[0] = v0;
    op[1] = v1;
  } else {
    // projection: relu tile [16x64] @ Wo [64x16] + bo
    short8 pa0 = *(const short8*)(aw + m16 * AST + quad * 8);
    short8 pa1 = *(const short8*)(aw + m16 * AST + 32 + quad * 8);
    const short8* pb = (const short8*)sBp;
    short8 pb0 = pb[0 * 64 + lane];
    short8 pb1 = pb[1 * 64 + lane];
    float bv = sbo[m16];
    f32x4 pacc = (f32x4){bv, bv, bv, bv};
    pacc = __builtin_amdgcn_mfma_f32_16x16x32_bf16(pa0, pb0, pacc, 0, 0, 0);
    pacc = __builtin_amdgcn_mfma_f32_16x16x32_bf16(pa1, pb1, pacc, 0, 0, 0);
    if (f32m) {
      float* o = (float*)outp;
#pragma unroll
      for (int r = 0; r < 4; ++r)
        o[(long)(nb + quad * 4 + r) * OD + m16] = pacc[r];
    } else {
      u16* o = (u16*)outp;
#pragma unroll
      for (int r = 0; r < 4; ++r)
        o[(long)(nb + quad * 4 + r) * OD + m16] = f2bf(pacc[r]);
    }
  }
}

extern "C" void kernel_launch(void* const* d_in, const int* in_sizes, int n_in,
                              void* d_out, int out_size, void* d_ws, size_t ws_size,
                              hipStream_t stream) {
  const void* x = d_in[0];
  const void* eidx = d_in[1];
  const void* Wl = d_in[2];
  const void* bl = d_in[3];
  const void* Wr = d_in[4];
  const void* Wo = d_in[5];
  const void* bo = d_in[6];

  char* w = (char*)d_ws;
  size_t off = 0;
  int* flags = (int*)(w + off);     off += 256;  // [0]=i32edge [1]=f32 [2]=done
  int* deg = (int*)(w + off);       off += (size_t)NN * 4 + 192;
  size_t memset_bytes = off;
  int* rowstart = (int*)(w + off);  off += (size_t)NN * 4 + 192;
  int* cursor = (int*)(w + off);    off += (size_t)NN * 4 + 192;
  float* rdeg = (float*)(w + off);  off += (size_t)NN * 4 + 192;
  int* bsum = (int*)(w + off);      off += 256 * 4;
  u16* wfrag = (u16*)(w + off);     off += 3 * 16 * 64 * 8 * 2;
  u16* pfrag = (u16*)(w + off);     off += 2 * 64 * 8 * 2;
  float* blf = (float*)(w + off);   off += 3 * HD * 4;
  float* bof = (float*)(w + off);   off += 256;
  int* csr = (int*)(w + off);       off += (size_t)NE * 4;
  u16* xA = (u16*)(w + off);        off += (size_t)NN * HD * 2;
  u16* xB = (u16*)(w + off);        off += (size_t)NN * HD * 2;
  u16* xC = (u16*)(w + off);        off += (size_t)NN * HD * 2;

  hipMemsetAsync(flags, 0, memset_bytes, stream);

  k_detect<<<256, 256, 0, stream>>>((const u32*)eidx, (const u16*)x, flags);
  k_prep<<<3125, 256, 0, stream>>>(x, eidx, Wl, bl, Wr, Wo, bo, deg, xA,
                                   wfrag, pfrag, blf, bof, flags);
  k_scanrow<<<NB, 256, 0, stream>>>(deg, bsum, &flags[2], rowstart, cursor, rdeg);
  k_fill<<<3125, 256, 0, stream>>>(eidx, cursor, csr, flags);

  // L0: (x|xA) -> xB ; L1: xB -> xC ; L2: xC -> d_out (fused projection)
  k_fused<<<FBLK, 256, 0, stream>>>((const u16*)x, xA, xB, rowstart, deg, rdeg,
                                    csr, wfrag, pfrag, blf, bof, (void*)0, 0, 0, flags);
  k_fused<<<FBLK, 256, 0, stream>>>(xB, xB, xC, rowstart, deg, rdeg,
                                    csr, wfrag, pfrag, blf, bof, (void*)0, 1, 0, flags);
  k_fused<<<FBLK, 256, 0, stream>>>(xC, xC, (u16*)0, rowstart, deg, rdeg,
                                    csr, wfrag, pfrag, blf, bof, d_out, 2, 1, flags);
}

// Round 6
// 223.218 us; speedup vs baseline: 4.4695x; 1.5446x over previous
//
#include <hip/hip_runtime.h>
#include <hip/hip_bf16.h>

#define NN 50000
#define NE 800000
#define HD 64
#define OD 16
#define CAP 64        // padded-CSR slots per node (mean deg = 16)
#define TILES 3125    // NN/16
#define AST 72        // LDS A/C row stride in u16 (144 B)

typedef unsigned short u16;
typedef unsigned int u32;
typedef __attribute__((ext_vector_type(8))) short short8;
typedef __attribute__((ext_vector_type(4))) float f32x4;

__device__ __forceinline__ float bf2f(u16 v) { return __uint_as_float(((u32)v) << 16); }
__device__ __forceinline__ u16 f2bf(float f) {
  __hip_bfloat16 h = __float2bfloat16(f);
  return *reinterpret_cast<u16*>(&h);
}
__device__ __forceinline__ float ldf(const void* p, long i, bool f32m) {
  return f32m ? ((const float*)p)[i] : bf2f(((const u16*)p)[i]);
}
__device__ __forceinline__ int edge_at(const void* eidx, long pos, bool i64) {
  return i64 ? (int)((const long long*)eidx)[pos] : ((const int*)eidx)[pos];
}

// ---- probe: int64-vs-int32 edges (flags[0]), f32-vs-bf16 floats (flags[1]) ----
__global__ void k_detect(const u32* __restrict__ e32, const u16* __restrict__ xu,
                         int* flags) {
  int i = blockIdx.x * blockDim.x + threadIdx.x;
  if (i < 4096) {
    if (e32[2 * i + 1] != 0u) atomicOr(&flags[0], 1);
  }
  if (i < 65536) {
    u16 v = xu[i];
    int e = (v >> 7) & 0xFF;
    if (v != 0 && (e < 100 || e > 140)) atomicAdd(&flags[1], 1);
  }
}

// ONE pass: padded-CSR build (deg counter doubles as slot cursor) + x->bf16
// (f32 mode) + MFMA B/proj fragment pre-arrangement + biases.
// grid: 3125*256 = 800000 == NE == NN*HD/4
__global__ __launch_bounds__(256) void k_prep(
    const void* __restrict__ x, const void* __restrict__ eidx,
    const void* __restrict__ Wl, const void* __restrict__ bl,
    const void* __restrict__ Wr, const void* __restrict__ Wo,
    const void* __restrict__ bo,
    int* __restrict__ deg, u16* __restrict__ csr, u32* __restrict__ spill,
    u16* __restrict__ xA, u16* __restrict__ wfrag, u16* __restrict__ pfrag,
    float* __restrict__ blf, float* __restrict__ bof,
    int* __restrict__ flags) {
  bool f32m = flags[1] > 1000;
  bool i64 = (flags[0] == 0);
  int i = blockIdx.x * blockDim.x + threadIdx.x;
  if (i < NE) {
    int src = edge_at(eidx, i, i64);
    int dst = edge_at(eidx, (long)NE + i, i64);
    int pos = atomicAdd(&deg[dst], 1);
    if (pos < CAP) {
      csr[(long)dst * CAP + pos] = (u16)src;
    } else {  // never for sane inputs; correct fallback
      int sp = atomicAdd(&flags[4], 1);
      spill[sp] = (u32)dst * 50000u + (u32)src;
    }
  }
  if (f32m) {
    float4 v = ((const float4*)x)[i];
    u32 lo = (u32)f2bf(v.x) | ((u32)f2bf(v.y) << 16);
    u32 hi = (u32)f2bf(v.z) | ((u32)f2bf(v.w) << 16);
    ((u32*)xA)[2 * i] = lo;
    ((u32*)xA)[2 * i + 1] = hi;
  }
  if (i < 3 * 16 * 64 * 8) {  // B frags: k=32s+(lane>>4)*8+j, n=16c+(lane&15)
    int j = i & 7, lane = (i >> 3) & 63, f = (i >> 9) & 15, l = i >> 13;
    int s = f >> 2, c = f & 3;
    int k = 32 * s + ((lane >> 4) << 3) + j;
    int n = (c << 4) + (lane & 15);
    long base = (long)l * HD * HD;
    float v = (k < HD) ? ldf(Wl, base + (long)k * HD + n, f32m)
                       : ldf(Wr, base + (long)(k - HD) * HD + n, f32m);
    wfrag[i] = f2bf(v);
  }
  if (i < 2 * 64 * 8) {  // proj frags
    int j = i & 7, lane = (i >> 3) & 63, s = i >> 9;
    int k = 32 * s + ((lane >> 4) << 3) + j;
    pfrag[i] = f2bf(ldf(Wo, (long)k * OD + (lane & 15), f32m));
  }
  if (i < 3 * HD) blf[i] = ldf(bl, i, f32m);
  if (i < OD) bof[i] = ldf(bo, i, f32m);
}

// fused SAGE layer: block = 4 waves = ONE 16-node tile.
// Each wave gathers 4 nodes (lane=feature) into shared LDS A-tile, then
// computes one 16-col slice of relu([agg|x] @ [Wl;Wr] + bl) via 4 MFMAs.
// doProj: wave 0 additionally computes out = relu_tile @ Wo + bo.
__global__ __launch_bounds__(256, 8) void k_fused(
    const u16* __restrict__ xin_bf, const u16* __restrict__ xin_f32m,
    u16* __restrict__ xout,
    const int* __restrict__ deg, const u16* __restrict__ csr,
    const u32* __restrict__ spill,
    const u16* __restrict__ wfrag, const u16* __restrict__ pfrag,
    const float* __restrict__ bl3, const float* __restrict__ bof,
    void* __restrict__ outp, int layer, int doProj,
    const int* __restrict__ flags) {
  __shared__ __align__(16) u16 aw[16 * AST];
  __shared__ float sbl[HD];
  __shared__ float sbo[OD];
  if (threadIdx.x < HD) sbl[threadIdx.x] = bl3[layer * HD + threadIdx.x];
  if (threadIdx.x < OD) sbo[threadIdx.x] = bof[threadIdx.x];
  bool f32m = flags[1] > 1000;
  int spillcnt = __builtin_amdgcn_readfirstlane(flags[4]);
  const u16* xin = f32m ? xin_f32m : xin_bf;

  int lane = threadIdx.x & 63;
  int w = threadIdx.x >> 6;
  int nb = blockIdx.x * 16;

  // ---- gather-mean: wave w handles nodes nb+4w .. nb+4w+3 ----
  for (int g = 0; g < 4; ++g) {
    int n = nb + 4 * w + g;
    int dtot = __builtin_amdgcn_readfirstlane(deg[n]);
    int d = dtot < CAP ? dtot : CAP;
    const u16* cr = csr + (long)n * CAP;
    float c0 = 0.f, c1 = 0.f, c2 = 0.f, c3 = 0.f;
    float c4 = 0.f, c5 = 0.f, c6 = 0.f, c7 = 0.f;
    {
      int idx = (lane < d) ? (int)cr[lane] : 0;
      int j = 0;
      for (; j + 7 < d; j += 8) {
        int s0 = __builtin_amdgcn_readlane(idx, j);
        int s1 = __builtin_amdgcn_readlane(idx, j + 1);
        int s2 = __builtin_amdgcn_readlane(idx, j + 2);
        int s3 = __builtin_amdgcn_readlane(idx, j + 3);
        int s4 = __builtin_amdgcn_readlane(idx, j + 4);
        int s5 = __builtin_amdgcn_readlane(idx, j + 5);
        int s6 = __builtin_amdgcn_readlane(idx, j + 6);
        int s7 = __builtin_amdgcn_readlane(idx, j + 7);
        c0 += bf2f(xin[(long)s0 * HD + lane]);
        c1 += bf2f(xin[(long)s1 * HD + lane]);
        c2 += bf2f(xin[(long)s2 * HD + lane]);
        c3 += bf2f(xin[(long)s3 * HD + lane]);
        c4 += bf2f(xin[(long)s4 * HD + lane]);
        c5 += bf2f(xin[(long)s5 * HD + lane]);
        c6 += bf2f(xin[(long)s6 * HD + lane]);
        c7 += bf2f(xin[(long)s7 * HD + lane]);
      }
      for (; j < d; ++j) {
        int s0 = __builtin_amdgcn_readlane(idx, j);
        c0 += bf2f(xin[(long)s0 * HD + lane]);
      }
    }
    float sum = ((c0 + c1) + (c2 + c3)) + ((c4 + c5) + (c6 + c7));
    if (spillcnt > 0) {  // cold path: only if some node exceeded CAP
      for (int base = 0; base < spillcnt; base += 64) {
        u32 p = (base + lane < spillcnt) ? spill[base + lane] : 0xffffffffu;
        u32 dd = p / 50000u;
        u32 ss = p - dd * 50000u;
        unsigned long long m = __ballot(dd == (u32)n);
        while (m) {
          int j = __builtin_ctzll(m);
          m &= m - 1;
          int s = __builtin_amdgcn_readlane((int)ss, j);
          sum += bf2f(xin[(long)s * HD + lane]);
        }
      }
    }
    float rd = 1.0f / (float)(dtot > 0 ? dtot : 1);
    aw[(4 * w + g) * AST + lane] = f2bf(sum * rd);
  }
  __syncthreads();

  // ---- A fragments (shared tile), B fragments straight from global ----
  int quad = lane >> 4, m16 = lane & 15;
  short8 a0 = *(const short8*)(aw + m16 * AST + quad * 8);        // k 0..31
  short8 a1 = *(const short8*)(aw + m16 * AST + 32 + quad * 8);   // k 32..63
  const u16* xrow = xin + (long)(nb + m16) * HD;
  short8 x2 = *(const short8*)(xrow + quad * 8);                  // k 64..95
  short8 x3 = *(const short8*)(xrow + 32 + quad * 8);             // k 96..127
  int c = w;  // this wave's col-tile
  const short8* bp = (const short8*)(wfrag + (long)layer * 16 * 64 * 8);
  short8 b0 = bp[(0 * 4 + c) * 64 + lane];
  short8 b1 = bp[(1 * 4 + c) * 64 + lane];
  short8 b2 = bp[(2 * 4 + c) * 64 + lane];
  short8 b3 = bp[(3 * 4 + c) * 64 + lane];
  float bb = sbl[c * 16 + m16];
  f32x4 acc = (f32x4){bb, bb, bb, bb};
  acc = __builtin_amdgcn_mfma_f32_16x16x32_bf16(a0, b0, acc, 0, 0, 0);
  acc = __builtin_amdgcn_mfma_f32_16x16x32_bf16(a1, b1, acc, 0, 0, 0);
  acc = __builtin_amdgcn_mfma_f32_16x16x32_bf16(x2, b2, acc, 0, 0, 0);
  acc = __builtin_amdgcn_mfma_f32_16x16x32_bf16(x3, b3, acc, 0, 0, 0);
  __syncthreads();  // all A reads done before C overwrites aw

  // ---- relu -> C staging (C layout: col=lane&15, row=quad*4+reg) ----
#pragma unroll
  for (int r = 0; r < 4; ++r)
    aw[(quad * 4 + r) * AST + c * 16 + m16] = f2bf(fmaxf(acc[r], 0.f));
  __syncthreads();

  if (!doProj) {
    // coalesced tile store: thread covers 8 B; row = tid>>4, chunk = tid&15
    int row = threadIdx.x >> 4, ch = threadIdx.x & 15;
    uint2 v = *(const uint2*)(aw + row * AST + ch * 4);
    *(uint2*)(xout + (long)(nb + row) * HD + ch * 4) = v;
  } else if (w == 0) {
    // projection: relu_tile [16x64] @ Wo [64x16] + bo
    short8 pa0 = *(const short8*)(aw + m16 * AST + quad * 8);
    short8 pa1 = *(const short8*)(aw + m16 * AST + 32 + quad * 8);
    const short8* pb = (const short8*)pfrag;
    short8 pb0 = pb[lane];
    short8 pb1 = pb[64 + lane];
    float bv = sbo[m16];
    f32x4 pacc = (f32x4){bv, bv, bv, bv};
    pacc = __builtin_amdgcn_mfma_f32_16x16x32_bf16(pa0, pb0, pacc, 0, 0, 0);
    pacc = __builtin_amdgcn_mfma_f32_16x16x32_bf16(pa1, pb1, pacc, 0, 0, 0);
    if (f32m) {
      float* o = (float*)outp;
#pragma unroll
      for (int r = 0; r < 4; ++r)
        o[(long)(nb + quad * 4 + r) * OD + m16] = pacc[r];
    } else {
      u16* o = (u16*)outp;
#pragma unroll
      for (int r = 0; r < 4; ++r)
        o[(long)(nb + quad * 4 + r) * OD + m16] = f2bf(pacc[r]);
    }
  }
}

extern "C" void kernel_launch(void* const* d_in, const int* in_sizes, int n_in,
                              void* d_out, int out_size, void* d_ws, size_t ws_size,
                              hipStream_t stream) {
  const void* x = d_in[0];
  const void* eidx = d_in[1];
  const void* Wl = d_in[2];
  const void* bl = d_in[3];
  const void* Wr = d_in[4];
  const void* Wo = d_in[5];
  const void* bo = d_in[6];

  char* w = (char*)d_ws;
  size_t off = 0;
  int* flags = (int*)(w + off);   off += 256;   // [0]=i32edge [1]=f32 [4]=spillcnt
  int* deg = (int*)(w + off);     off += (size_t)NN * 4 + 192;
  size_t memset_bytes = off;                    // one memset covers flags+deg
  u16* csr = (u16*)(w + off);     off += (size_t)NN * CAP * 2;   // 6.4 MB
  u32* spill = (u32*)(w + off);   off += (size_t)NE * 4;         // 3.2 MB
  u16* wfrag = (u16*)(w + off);   off += 3 * 16 * 64 * 8 * 2;
  u16* pfrag = (u16*)(w + off);   off += 2 * 64 * 8 * 2;
  float* blf = (float*)(w + off); off += 3 * HD * 4;
  float* bof = (float*)(w + off); off += 256;
  u16* xA = (u16*)(w + off);      off += (size_t)NN * HD * 2;
  u16* xB = (u16*)(w + off);      off += (size_t)NN * HD * 2;

  hipMemsetAsync(flags, 0, memset_bytes, stream);

  k_detect<<<256, 256, 0, stream>>>((const u32*)eidx, (const u16*)x, flags);
  k_prep<<<3125, 256, 0, stream>>>(x, eidx, Wl, bl, Wr, Wo, bo, deg, csr, spill,
                                   xA, wfrag, pfrag, blf, bof, flags);

  // L0: (x|xA) -> xB ; L1: xB -> xA ; L2: xA -> d_out (fused projection)
  k_fused<<<TILES, 256, 0, stream>>>((const u16*)x, xA, xB, deg, csr, spill,
                                     wfrag, pfrag, blf, bof, (void*)0, 0, 0, flags);
  k_fused<<<TILES, 256, 0, stream>>>(xB, xB, xA, deg, csr, spill,
                                     wfrag, pfrag, blf, bof, (void*)0, 1, 0, flags);
  k_fused<<<TILES, 256, 0, stream>>>(xA, xA, (u16*)0, deg, csr, spill,
                                     wfrag, pfrag, blf, bof, d_out, 2, 1, flags);
}